// Round 2
// baseline (4686.778 us; speedup 1.0000x reference)
//
#include <hip/hip_runtime.h>
#include <cstdint>

#define N_ML 8  // MAX_LEN

__device__ __forceinline__ float fsigmoid(float x) { return 1.f / (1.f + __expf(-x)); }
__device__ __forceinline__ float ftanh_(float x) {
    float e = __expf(-2.f * fabsf(x));
    float t = (1.f - e) / (1.f + e);
    return x >= 0.f ? t : -t;
}
__device__ __forceinline__ float fselu(float x) {
    const float sc = 1.0507009873554805f, al = 1.6732632423543772f;
    return x > 0.f ? sc * x : sc * al * (__expf(x) - 1.f);
}

// ---- prep: fold edge MLP (linear x linear) into one matrix ----
__global__ void prep_we_kernel(const float* __restrict__ ew1, const float* __restrict__ eb1,
                               const float* __restrict__ ew2, const float* __restrict__ eb2,
                               float* __restrict__ We, float* __restrict__ be) {
    int t = blockIdx.x * 256 + threadIdx.x;
    if (t < 4096) {
        int k = t >> 5, j = t & 31;
        float a = 0.f;
        for (int i = 0; i < 32; ++i) a = fmaf(ew1[k * 32 + i], ew2[i * 32 + j], a);
        We[t] = a;
    }
    if (blockIdx.x == 0 && threadIdx.x < 32) {
        int j = threadIdx.x;
        float a = eb2[j];
        for (int i = 0; i < 32; ++i) a = fmaf(eb1[i], ew2[i * 32 + j], a);
        be[j] = a;
    }
}

// ---- init states (buffers pre-zeroed by memset) ----
__global__ void init_states_kernel(const float* __restrict__ li, const float* __restrict__ ni,
                                   const float* __restrict__ pi, float* __restrict__ ls,
                                   float* __restrict__ ns, float* __restrict__ ps,
                                   int n_links, int n_nodes, int n_paths) {
    int t = blockIdx.x * 256 + threadIdx.x;
    if (t < n_links) ls[(size_t)t * 32] = li[t];
    if (t < n_nodes) ns[(size_t)t * 32] = ni[t];
    if (t < n_paths) {
        ps[(size_t)t * 64] = pi[t];
        ps[(size_t)t * 64 + 1] = pi[n_paths + t];
    }
}

// ---- inverse scatter index: idx[p][s] = e, lens[p] = count ----
__global__ void build_idx_kernel(const int* __restrict__ paths, const int* __restrict__ seqs,
                                 int* __restrict__ idx, int* __restrict__ lens, int E) {
    int e = blockIdx.x * 256 + threadIdx.x;
    if (e < E) {
        int p = paths[e], s = seqs[e];
        idx[(size_t)p * N_ML + s] = e;
        atomicAdd(&lens[p], 1);
    }
}

// ---- GRU scan, lane = path; weights via wave-uniform scalar loads ----
// Block: 512 thr = 8 waves; 64 paths/block (one per lane). Wave w owns gate
// dims d = w*8..w*8+7 for all three gates (z at d, r at 64+d, c at 128+d),
// so the nonlinearity needs no cross-wave exchange. x,h tiles in LDS [k][p].
extern "C" __global__ void __launch_bounds__(512, 4)
gru_kernel(const float* __restrict__ ls, const float* __restrict__ ns,
           float* __restrict__ ps, float* __restrict__ m,
           const int* __restrict__ idx, const int* __restrict__ lens,
           const int* __restrict__ l2p, const int* __restrict__ n2p,
           const float* __restrict__ wx, const float* __restrict__ wh,
           const float* __restrict__ gb, int n_paths) {
    __shared__ float x_l[64 * 64];
    __shared__ float h_l[64 * 64];
    const int tid = threadIdx.x;
    const int wv = tid >> 6, lane = tid & 63;
    const int w8 = wv * 8;
    const int pi = blockIdx.x * 64 + lane;
    const bool ok = pi < n_paths;
    const int plen = ok ? lens[pi] : 0;

    // init h rows owned by this wave from path_state
#pragma unroll
    for (int di = 0; di < 8; ++di) {
        int d = w8 + di;
        h_l[d * 64 + lane] = ok ? ps[(size_t)pi * 64 + d] : 0.f;
    }

    int linkc = 0;
    bool ev = false;
    // gather step-t inputs into x_l (wave w writes k-rows w*8..w*8+7)
    auto gather = [&](int t) {
        int e = ok ? idx[(size_t)pi * N_ML + t] : -1;
        ev = (e >= 0);
        float4 v0 = make_float4(0.f, 0.f, 0.f, 0.f), v1 = v0;
        if (ev) {
            linkc = l2p[e];
            if (wv < 4) {
                const float* src = ls + (size_t)linkc * 32 + w8;
                v0 = *(const float4*)src;
                v1 = *(const float4*)(src + 4);
            } else {
                const float* src = ns + (size_t)n2p[e] * 32 + (w8 - 32);
                v0 = *(const float4*)src;
                v1 = *(const float4*)(src + 4);
            }
        }
        x_l[(w8 + 0) * 64 + lane] = v0.x;
        x_l[(w8 + 1) * 64 + lane] = v0.y;
        x_l[(w8 + 2) * 64 + lane] = v0.z;
        x_l[(w8 + 3) * 64 + lane] = v0.w;
        x_l[(w8 + 4) * 64 + lane] = v1.x;
        x_l[(w8 + 5) * 64 + lane] = v1.y;
        x_l[(w8 + 6) * 64 + lane] = v1.z;
        x_l[(w8 + 7) * 64 + lane] = v1.w;
    };
    gather(0);
    __syncthreads();

    for (int t = 0; t < N_ML; ++t) {
        float az[8], ar[8], ah[8], bz[8], br[8], bh[8];
#pragma unroll
        for (int oi = 0; oi < 8; ++oi) {
            az[oi] = gb[w8 + oi];
            ar[oi] = gb[64 + w8 + oi];
            ah[oi] = gb[128 + w8 + oi];
            bz[oi] = gb[192 + w8 + oi];
            br[oi] = gb[192 + 64 + w8 + oi];
            bh[oi] = gb[192 + 128 + w8 + oi];
        }
        for (int k = 0; k < 64; ++k) {
            float xk = x_l[k * 64 + lane];
            float hk = h_l[k * 64 + lane];
            const float* wxk = wx + k * 192 + w8;  // wave-uniform -> s_load
            const float* whk = wh + k * 192 + w8;
#pragma unroll
            for (int oi = 0; oi < 8; ++oi) {
                az[oi] = fmaf(xk, wxk[oi], az[oi]);
                ar[oi] = fmaf(xk, wxk[64 + oi], ar[oi]);
                ah[oi] = fmaf(xk, wxk[128 + oi], ah[oi]);
                bz[oi] = fmaf(hk, whk[oi], bz[oi]);
                br[oi] = fmaf(hk, whk[64 + oi], br[oi]);
                bh[oi] = fmaf(hk, whk[128 + oi], bh[oi]);
            }
        }
        __syncthreads();  // all reads of x_l/h_l done
        bool msk = t < plen;
#pragma unroll
        for (int oi = 0; oi < 8; ++oi) {
            int d = w8 + oi;
            float hold = h_l[d * 64 + lane];
            float z = fsigmoid(az[oi] + bz[oi]);
            float r = fsigmoid(ar[oi] + br[oi]);
            float c = ftanh_(ah[oi] + r * bh[oi]);
            float hn = z * hold + (1.f - z) * c;
            h_l[d * 64 + lane] = msk ? hn : hold;
            if (ev && msk) atomicAdd(&m[(size_t)linkc * 64 + d], hn);
        }
        if (t < N_ML - 1) gather(t + 1);
        __syncthreads();
    }
    if (ok) {
#pragma unroll
        for (int di = 0; di < 8; ++di) {
            int d = w8 + di;
            ps[(size_t)pi * 64 + d] = h_l[d * 64 + lane];
        }
    }
}

// ---- edge MLP (pre-folded): ls_new = con @ We + be ----
extern "C" __global__ void __launch_bounds__(256, 2)
edge_kernel(const float* __restrict__ ns, const float* __restrict__ lso,
            const float* __restrict__ m, const float* __restrict__ We,
            const float* __restrict__ be, const int* __restrict__ l2n,
            float* __restrict__ lsn, int n_links) {
    __shared__ float We_l[4096];
    __shared__ float be_l[32];
    __shared__ float con_l[8][128];
    int tid = threadIdx.x;
    for (int i = tid; i < 4096; i += 256) We_l[i] = We[i];
    if (tid < 32) be_l[tid] = be[tid];
    int li = tid >> 5, o = tid & 31;
    int l = blockIdx.x * 8 + li;
    if (l < n_links) {
        con_l[li][o] = ns[(size_t)l2n[l] * 32 + o];
        con_l[li][32 + o] = lso[(size_t)l * 32 + o];
        con_l[li][64 + o] = m[(size_t)l * 64 + o];
        con_l[li][96 + o] = m[(size_t)l * 64 + 32 + o];
    }
    __syncthreads();
    if (l >= n_links) return;
    float acc = be_l[o];
#pragma unroll 8
    for (int k = 0; k < 128; ++k) acc = fmaf(con_l[li][k], We_l[k * 32 + o], acc);
    lsn[(size_t)l * 32 + o] = acc;
}

// ---- ECCConv: lane = link, wk via scalar loads, i-split over 4 waves ----
extern "C" __global__ void __launch_bounds__(256, 4)
ecc_kernel(const float* __restrict__ lsn, const float* __restrict__ ns,
           const float* __restrict__ wk, const float* __restrict__ bk,
           const int* __restrict__ senders, const int* __restrict__ receivers,
           float* __restrict__ agg, int n_links) {
    __shared__ float lt[32 * 64];       // [j][link]
    __shared__ float part[4][32 * 64];  // [wave][o][link]
    const int tid = threadIdx.x;
    const int wv = tid >> 6, lane = tid & 63;
    const int w8 = wv * 8;
    const int l = blockIdx.x * 64 + lane;
    const bool ok = l < n_links;

    float4 a0 = make_float4(0.f, 0.f, 0.f, 0.f), a1 = a0;
    if (ok) {
        const float* src = lsn + (size_t)l * 32 + w8;
        a0 = *(const float4*)src;
        a1 = *(const float4*)(src + 4);
    }
    lt[(w8 + 0) * 64 + lane] = a0.x;
    lt[(w8 + 1) * 64 + lane] = a0.y;
    lt[(w8 + 2) * 64 + lane] = a0.z;
    lt[(w8 + 3) * 64 + lane] = a0.w;
    lt[(w8 + 4) * 64 + lane] = a1.x;
    lt[(w8 + 5) * 64 + lane] = a1.y;
    lt[(w8 + 6) * 64 + lane] = a1.z;
    lt[(w8 + 7) * 64 + lane] = a1.w;

    float ni[8];
    if (ok) {
        const float* src = ns + (size_t)senders[l] * 32 + w8;
        float4 n0 = *(const float4*)src;
        float4 n1 = *(const float4*)(src + 4);
        ni[0] = n0.x; ni[1] = n0.y; ni[2] = n0.z; ni[3] = n0.w;
        ni[4] = n1.x; ni[5] = n1.y; ni[6] = n1.z; ni[7] = n1.w;
    } else {
#pragma unroll
        for (int i = 0; i < 8; ++i) ni[i] = 0.f;
    }
    __syncthreads();

    float acc[32];
#pragma unroll
    for (int o = 0; o < 32; ++o) acc[o] = 0.f;
    // bias part: sum_i ni[i] * bk[(w8+i)*32+o]
#pragma unroll 2
    for (int i = 0; i < 8; ++i) {
        const float* bki = bk + (w8 + i) * 32;  // uniform -> s_load
#pragma unroll
        for (int o = 0; o < 32; ++o) acc[o] = fmaf(ni[i], bki[o], acc[o]);
    }
    for (int j = 0; j < 32; ++j) {
        float lj = lt[j * 64 + lane];
#pragma unroll 2
        for (int i = 0; i < 8; ++i) {
            float pij = lj * ni[i];
            const float* wkji = wk + (size_t)j * 1024 + (w8 + i) * 32;  // uniform -> s_load
#pragma unroll
            for (int o = 0; o < 32; ++o) acc[o] = fmaf(pij, wkji[o], acc[o]);
        }
    }
#pragma unroll
    for (int o = 0; o < 32; ++o) part[wv][o * 64 + lane] = acc[o];
    __syncthreads();
    if (ok) {
        int rcv = receivers[l];
#pragma unroll
        for (int oi = 0; oi < 8; ++oi) {
            int o = w8 + oi;
            float s = part[0][o * 64 + lane] + part[1][o * 64 + lane] +
                      part[2][o * 64 + lane] + part[3][o * 64 + lane];
            atomicAdd(&agg[(size_t)rcv * 32 + o], s);
        }
    }
}

// ---- node update: ns_new = agg + ns_old @ wroot + broot ----
extern "C" __global__ void __launch_bounds__(256, 2)
node_kernel(const float* __restrict__ agg, const float* __restrict__ nso,
            const float* __restrict__ wroot, const float* __restrict__ broot,
            float* __restrict__ nsn, int n_nodes) {
    __shared__ float wr_l[1024];
    __shared__ float ns_s[8][32];
    int tid = threadIdx.x;
    for (int i = tid; i < 1024; i += 256) wr_l[i] = wroot[i];
    int ni = tid >> 5, o = tid & 31;
    int n = blockIdx.x * 8 + ni;
    if (n < n_nodes) ns_s[ni][o] = nso[(size_t)n * 32 + o];
    __syncthreads();
    if (n >= n_nodes) return;
    float acc = agg[(size_t)n * 32 + o] + broot[o];
#pragma unroll 8
    for (int k = 0; k < 32; ++k) acc = fmaf(ns_s[ni][k], wr_l[k * 32 + o], acc);
    nsn[(size_t)n * 32 + o] = acc;
}

// ---- readout: selu MLP + final head, 32 lanes per path ----
extern "C" __global__ void __launch_bounds__(256, 2)
readout_kernel(const float* __restrict__ ps, const float* __restrict__ w1,
               const float* __restrict__ b1, const float* __restrict__ w2,
               const float* __restrict__ b2, const float* __restrict__ fw,
               const float* __restrict__ fb, float* __restrict__ out, int n_paths) {
    __shared__ float w1_l[2048];
    __shared__ float w2_l[1024];
    __shared__ float fw_l[96];
    __shared__ float b1_l[32], b2_l[32];
    __shared__ float h_s[8][64];
    __shared__ float r1_s[8][32];
    int tid = threadIdx.x;
    for (int i = tid; i < 2048; i += 256) w1_l[i] = w1[i];
    for (int i = tid; i < 1024; i += 256) w2_l[i] = w2[i];
    if (tid < 96) fw_l[tid] = fw[tid];
    if (tid < 32) { b1_l[tid] = b1[tid]; b2_l[tid] = b2[tid]; }
    int li = tid >> 5, j = tid & 31;
    int p = blockIdx.x * 8 + li;
    bool ok = (p < n_paths);
    if (ok) {
        h_s[li][j] = ps[(size_t)p * 64 + j];
        h_s[li][32 + j] = ps[(size_t)p * 64 + 32 + j];
    }
    __syncthreads();
    float a = b1_l[j];
#pragma unroll 8
    for (int k = 0; k < 64; ++k) a = fmaf(h_s[li][k], w1_l[k * 32 + j], a);
    r1_s[li][j] = fselu(a);
    __syncthreads();
    float b = b2_l[j];
#pragma unroll 8
    for (int k = 0; k < 32; ++k) b = fmaf(r1_s[li][k], w2_l[k * 32 + j], b);
    float part = fselu(b) * fw_l[j] + h_s[li][j] * fw_l[32 + j] + h_s[li][32 + j] * fw_l[64 + j];
#pragma unroll
    for (int off = 16; off > 0; off >>= 1) part += __shfl_down(part, off, 32);
    if (j == 0 && ok) out[p] = part + fb[0];
}

extern "C" void kernel_launch(void* const* d_in, const int* in_sizes, int n_in,
                              void* d_out, int out_size, void* d_ws, size_t ws_size,
                              hipStream_t stream) {
    const float* link_init = (const float*)d_in[0];
    const float* node_init = (const float*)d_in[1];
    const float* path_init = (const float*)d_in[2];
    const float* gru_wx = (const float*)d_in[3];
    const float* gru_wh = (const float*)d_in[4];
    const float* gru_b = (const float*)d_in[5];
    const float* e_w1 = (const float*)d_in[6];
    const float* e_b1 = (const float*)d_in[7];
    const float* e_w2 = (const float*)d_in[8];
    const float* e_b2 = (const float*)d_in[9];
    const float* ecc_wk = (const float*)d_in[10];
    const float* ecc_bk = (const float*)d_in[11];
    const float* ecc_wroot = (const float*)d_in[12];
    const float* ecc_broot = (const float*)d_in[13];
    const float* r_w1 = (const float*)d_in[14];
    const float* r_b1 = (const float*)d_in[15];
    const float* r_w2 = (const float*)d_in[16];
    const float* r_b2 = (const float*)d_in[17];
    const float* f_w = (const float*)d_in[18];
    const float* f_b = (const float*)d_in[19];
    const int* p2l = (const int*)d_in[20];
    const int* sseq = (const int*)d_in[21];
    const int* l2p = (const int*)d_in[22];
    const int* n2p = (const int*)d_in[23];
    const int* l2n = (const int*)d_in[24];
    const int* senders = (const int*)d_in[25];
    const int* receivers = (const int*)d_in[26];

    const int nl = in_sizes[0];
    const int nn = in_sizes[1];
    const int np = in_sizes[2] / 2;
    const int E = in_sizes[20];

    char* base = (char*)d_ws;
    size_t off = 0;
    auto give = [&](size_t nbytes) -> void* {
        void* p = base + off;
        off += (nbytes + 255) & ~(size_t)255;
        return p;
    };
    float* ls0 = (float*)give((size_t)nl * 32 * 4);
    float* ls1 = (float*)give((size_t)nl * 32 * 4);
    float* ns0 = (float*)give((size_t)nn * 32 * 4);
    float* ns1 = (float*)give((size_t)nn * 32 * 4);
    float* ps = (float*)give((size_t)np * 64 * 4);
    float* m = (float*)give((size_t)nl * 64 * 4);
    float* agg = (float*)give((size_t)nn * 32 * 4);
    float* We = (float*)give(4096 * 4);
    float* be = (float*)give(32 * 4);
    int* idx = (int*)give((size_t)np * N_ML * 4);
    int* lensb = (int*)give((size_t)np * 4);
    float* lsb[2] = {ls0, ls1};
    float* nsb[2] = {ns0, ns1};

    hipMemsetAsync(ls0, 0, (size_t)nl * 32 * 4, stream);
    hipMemsetAsync(ns0, 0, (size_t)nn * 32 * 4, stream);
    hipMemsetAsync(ps, 0, (size_t)np * 64 * 4, stream);
    hipMemsetAsync(idx, 0xFF, (size_t)np * N_ML * 4, stream);
    hipMemsetAsync(lensb, 0, (size_t)np * 4, stream);

    prep_we_kernel<<<16, 256, 0, stream>>>(e_w1, e_b1, e_w2, e_b2, We, be);
    init_states_kernel<<<(np + 255) / 256, 256, 0, stream>>>(link_init, node_init, path_init,
                                                             ls0, ns0, ps, nl, nn, np);
    build_idx_kernel<<<(E + 255) / 256, 256, 0, stream>>>(p2l, sseq, idx, lensb, E);

    int cur = 0;
    for (int it = 0; it < 2; ++it) {
        hipMemsetAsync(m, 0, (size_t)nl * 64 * 4, stream);
        gru_kernel<<<(np + 63) / 64, 512, 0, stream>>>(lsb[cur], nsb[cur], ps, m, idx, lensb,
                                                       l2p, n2p, gru_wx, gru_wh, gru_b, np);
        edge_kernel<<<(nl + 7) / 8, 256, 0, stream>>>(nsb[cur], lsb[cur], m, We, be, l2n,
                                                      lsb[1 - cur], nl);
        hipMemsetAsync(agg, 0, (size_t)nn * 32 * 4, stream);
        ecc_kernel<<<(nl + 63) / 64, 256, 0, stream>>>(lsb[1 - cur], nsb[cur], ecc_wk, ecc_bk,
                                                       senders, receivers, agg, nl);
        node_kernel<<<(nn + 7) / 8, 256, 0, stream>>>(agg, nsb[cur], ecc_wroot, ecc_broot,
                                                      nsb[1 - cur], nn);
        cur ^= 1;
    }
    readout_kernel<<<(np + 7) / 8, 256, 0, stream>>>(ps, r_w1, r_b1, r_w2, r_b2, f_w, f_b,
                                                     (float*)d_out, np);
}

// Round 3
// 965.825 us; speedup vs baseline: 4.8526x; 4.8526x over previous
//
#include <hip/hip_runtime.h>
#include <cstdint>

#define N_ML 8  // MAX_LEN
#define ECC_SMEM (32768 * 4)  // 128 KB dynamic LDS for ecc weight staging
#define HSTR 72               // h_lds row stride in bf16 elements (144B: 2-way-free banks)

typedef __attribute__((ext_vector_type(8))) short bf16x8;
typedef __attribute__((ext_vector_type(4))) float f32x4;

__device__ __forceinline__ float fsigmoid(float x) { return 1.f / (1.f + __expf(-x)); }
__device__ __forceinline__ float ftanh_(float x) {
    float e = __expf(-2.f * fabsf(x));
    float t = (1.f - e) / (1.f + e);
    return x >= 0.f ? t : -t;
}
__device__ __forceinline__ float fselu(float x) {
    const float sc = 1.0507009873554805f, al = 1.6732632423543772f;
    return x > 0.f ? sc * x : sc * al * (__expf(x) - 1.f);
}
// f32 -> bf16 RTNE
__device__ __forceinline__ unsigned short f2bf(float f) {
    union { float f; unsigned int u; } v;
    v.f = f;
    unsigned int u = v.u;
    return (unsigned short)((u + 0x7FFFu + ((u >> 16) & 1u)) >> 16);
}
__device__ __forceinline__ bf16x8 pack8(float4 a, float4 b) {
    bf16x8 r;
    r[0] = (short)f2bf(a.x); r[1] = (short)f2bf(a.y);
    r[2] = (short)f2bf(a.z); r[3] = (short)f2bf(a.w);
    r[4] = (short)f2bf(b.x); r[5] = (short)f2bf(b.y);
    r[6] = (short)f2bf(b.z); r[7] = (short)f2bf(b.w);
    return r;
}

// ---- prep: fold edge MLP (linear x linear) into one matrix ----
__global__ void prep_we_kernel(const float* __restrict__ ew1, const float* __restrict__ eb1,
                               const float* __restrict__ ew2, const float* __restrict__ eb2,
                               float* __restrict__ We, float* __restrict__ be) {
    int t = blockIdx.x * 256 + threadIdx.x;
    if (t < 4096) {
        int k = t >> 5, j = t & 31;
        float a = 0.f;
        for (int i = 0; i < 32; ++i) a = fmaf(ew1[k * 32 + i], ew2[i * 32 + j], a);
        We[t] = a;
    }
    if (blockIdx.x == 0 && threadIdx.x < 32) {
        int j = threadIdx.x;
        float a = eb2[j];
        for (int i = 0; i < 32; ++i) a = fmaf(eb1[i], ew2[i * 32 + j], a);
        be[j] = a;
    }
}

// ---- init states (buffers pre-zeroed by memset) ----
__global__ void init_states_kernel(const float* __restrict__ li, const float* __restrict__ ni,
                                   const float* __restrict__ pi, float* __restrict__ ls,
                                   float* __restrict__ ns, float* __restrict__ ps,
                                   int n_links, int n_nodes, int n_paths) {
    int t = blockIdx.x * 256 + threadIdx.x;
    if (t < n_links) ls[(size_t)t * 32] = li[t];
    if (t < n_nodes) ns[(size_t)t * 32] = ni[t];
    if (t < n_paths) {
        ps[(size_t)t * 64] = pi[t];
        ps[(size_t)t * 64 + 1] = pi[n_paths + t];
    }
}

// ---- per-(path,slot) link/node id tables (gl/gn pre-memset to -1) ----
__global__ void build_idx_kernel(const int* __restrict__ paths, const int* __restrict__ seqs,
                                 const int* __restrict__ l2p, const int* __restrict__ n2p,
                                 int* __restrict__ gl, int* __restrict__ gn,
                                 int* __restrict__ lens, int E) {
    int e = blockIdx.x * 256 + threadIdx.x;
    if (e < E) {
        int p = paths[e], s = seqs[e];
        gl[(size_t)p * N_ML + s] = l2p[e];
        gn[(size_t)p * N_ML + s] = n2p[e];
        atomicAdd(&lens[p], 1);
    }
}

// ---- GRU scan via MFMA: 64 paths/block, 8 waves = 2 Mgroups x 4 dimblocks ----
// B (weights bf16) in VGPRs; x-frags direct from global (L2); h via 9KB LDS.
extern "C" __global__ void __launch_bounds__(512, 2)
gru_kernel(const float* __restrict__ ls, const float* __restrict__ ns,
           float* __restrict__ ps, float* __restrict__ m,
           const int* __restrict__ gl, const int* __restrict__ gn,
           const int* __restrict__ lens,
           const float* __restrict__ wx, const float* __restrict__ wh,
           const float* __restrict__ gb, int n_paths) {
    __shared__ unsigned short h_lds[64 * HSTR];
    const int tid = threadIdx.x;
    const int lane = tid & 63;
    const int wv = tid >> 6;
    const int nw = wv & 3;   // dim-block 0..3 (16 dims each)
    const int mg = wv >> 2;  // M-group 0..1 (32 paths each)
    const int l15 = lane & 15;
    const int kg = lane >> 4;  // 0..3
    const int pblk = blockIdx.x * 64;
    const int d = nw * 16 + l15;  // output dim 0..63

    // ---- B fragments: lane holds W[k][col], k = kt*32 + kg*8 + j ----
    bf16x8 Bz[4], Br[4], Bcx[2], Bch[2];
#pragma unroll
    for (int kt = 0; kt < 4; ++kt) {
        int kb = kt * 32 + kg * 8;
        const float* W = (kb < 64) ? (wx + (size_t)kb * 192) : (wh + (size_t)(kb - 64) * 192);
        bf16x8 vz, vr, vc;
#pragma unroll
        for (int j = 0; j < 8; ++j) {
            vz[j] = (short)f2bf(W[j * 192 + d]);
            vr[j] = (short)f2bf(W[j * 192 + 64 + d]);
            vc[j] = (short)f2bf(W[j * 192 + 128 + d]);
        }
        Bz[kt] = vz;
        Br[kt] = vr;
        if (kt < 2) Bcx[kt] = vc; else Bch[kt - 2] = vc;
    }
    const float bias_z = gb[d] + gb[192 + d];
    const float bias_r = gb[64 + d] + gb[192 + 64 + d];
    const float bias_xh = gb[128 + d];
    const float bias_hh = gb[192 + 128 + d];

    // ---- A-side link/node id prefetch: row = pblk + mg*32 + mt*16 + l15 ----
    int glA[2][N_ML], gnA[2][N_ML];
#pragma unroll
    for (int mt = 0; mt < 2; ++mt) {
        int prow = pblk + mg * 32 + mt * 16 + l15;
        bool v = prow < n_paths;
        size_t pr = (size_t)(v ? prow : 0) * N_ML;
        int4 g0 = ((const int4*)(gl + pr))[0];
        int4 g1 = ((const int4*)(gl + pr))[1];
        int4 n0 = ((const int4*)(gn + pr))[0];
        int4 n1 = ((const int4*)(gn + pr))[1];
        glA[mt][0] = v ? g0.x : -1; glA[mt][1] = v ? g0.y : -1;
        glA[mt][2] = v ? g0.z : -1; glA[mt][3] = v ? g0.w : -1;
        glA[mt][4] = v ? g1.x : -1; glA[mt][5] = v ? g1.y : -1;
        glA[mt][6] = v ? g1.z : -1; glA[mt][7] = v ? g1.w : -1;
        gnA[mt][0] = v ? n0.x : -1; gnA[mt][1] = v ? n0.y : -1;
        gnA[mt][2] = v ? n0.z : -1; gnA[mt][3] = v ? n0.w : -1;
        gnA[mt][4] = v ? n1.x : -1; gnA[mt][5] = v ? n1.y : -1;
        gnA[mt][6] = v ? n1.z : -1; gnA[mt][7] = v ? n1.w : -1;
    }

    // ---- C-side state: path = pblk + mg*32 + mt*16 + kg*4 + i ----
    f32x4 hv[2];
    int plen_[2][4];
#pragma unroll
    for (int mt = 0; mt < 2; ++mt) {
#pragma unroll
        for (int i = 0; i < 4; ++i) {
            int pc = pblk + mg * 32 + mt * 16 + kg * 4 + i;
            bool v = pc < n_paths;
            hv[mt][i] = v ? ps[(size_t)pc * 64 + d] : 0.f;
            plen_[mt][i] = v ? lens[pc] : 0;
            h_lds[(mg * 32 + mt * 16 + kg * 4 + i) * HSTR + d] = f2bf(hv[mt][i]);
        }
    }
    __syncthreads();

#pragma unroll
    for (int t = 0; t < N_ML; ++t) {
        // x fragments (direct from global; L2-resident)
        bf16x8 ax0[2], ax1[2];
#pragma unroll
        for (int mt = 0; mt < 2; ++mt) {
            int lk = glA[mt][t], nd = gnA[mt][t];
            float4 f0 = make_float4(0.f, 0.f, 0.f, 0.f), f1 = f0, f2 = f0, f3 = f0;
            if (lk >= 0) {
                const float4* s = (const float4*)(ls + (size_t)lk * 32 + kg * 8);
                f0 = s[0]; f1 = s[1];
                const float4* q = (const float4*)(ns + (size_t)nd * 32 + kg * 8);
                f2 = q[0]; f3 = q[1];
            }
            ax0[mt] = pack8(f0, f1);
            ax1[mt] = pack8(f2, f3);
        }
        // h fragments from LDS
        bf16x8 ah0[2], ah1[2];
#pragma unroll
        for (int mt = 0; mt < 2; ++mt) {
            int row = mg * 32 + mt * 16 + l15;
            ah0[mt] = *(const bf16x8*)(h_lds + row * HSTR + kg * 8);
            ah1[mt] = *(const bf16x8*)(h_lds + row * HSTR + 32 + kg * 8);
        }
        // MFMA: D[path][dim]
        f32x4 accZ[2], accR[2], accXH[2], accHH[2];
#pragma unroll
        for (int mt = 0; mt < 2; ++mt) {
            accZ[mt] = f32x4{bias_z, bias_z, bias_z, bias_z};
            accR[mt] = f32x4{bias_r, bias_r, bias_r, bias_r};
            accXH[mt] = f32x4{bias_xh, bias_xh, bias_xh, bias_xh};
            accHH[mt] = f32x4{bias_hh, bias_hh, bias_hh, bias_hh};
            accZ[mt] = __builtin_amdgcn_mfma_f32_16x16x32_bf16(ax0[mt], Bz[0], accZ[mt], 0, 0, 0);
            accZ[mt] = __builtin_amdgcn_mfma_f32_16x16x32_bf16(ax1[mt], Bz[1], accZ[mt], 0, 0, 0);
            accZ[mt] = __builtin_amdgcn_mfma_f32_16x16x32_bf16(ah0[mt], Bz[2], accZ[mt], 0, 0, 0);
            accZ[mt] = __builtin_amdgcn_mfma_f32_16x16x32_bf16(ah1[mt], Bz[3], accZ[mt], 0, 0, 0);
            accR[mt] = __builtin_amdgcn_mfma_f32_16x16x32_bf16(ax0[mt], Br[0], accR[mt], 0, 0, 0);
            accR[mt] = __builtin_amdgcn_mfma_f32_16x16x32_bf16(ax1[mt], Br[1], accR[mt], 0, 0, 0);
            accR[mt] = __builtin_amdgcn_mfma_f32_16x16x32_bf16(ah0[mt], Br[2], accR[mt], 0, 0, 0);
            accR[mt] = __builtin_amdgcn_mfma_f32_16x16x32_bf16(ah1[mt], Br[3], accR[mt], 0, 0, 0);
            accXH[mt] = __builtin_amdgcn_mfma_f32_16x16x32_bf16(ax0[mt], Bcx[0], accXH[mt], 0, 0, 0);
            accXH[mt] = __builtin_amdgcn_mfma_f32_16x16x32_bf16(ax1[mt], Bcx[1], accXH[mt], 0, 0, 0);
            accHH[mt] = __builtin_amdgcn_mfma_f32_16x16x32_bf16(ah0[mt], Bch[0], accHH[mt], 0, 0, 0);
            accHH[mt] = __builtin_amdgcn_mfma_f32_16x16x32_bf16(ah1[mt], Bch[1], accHH[mt], 0, 0, 0);
        }
        __syncthreads();  // all h_lds reads of step t done
        // nonlinearity + state update + m scatter (C layout: col=l15, row=kg*4+i)
#pragma unroll
        for (int mt = 0; mt < 2; ++mt) {
#pragma unroll
            for (int i = 0; i < 4; ++i) {
                float z = fsigmoid(accZ[mt][i]);
                float r = fsigmoid(accR[mt][i]);
                float c = ftanh_(accXH[mt][i] + r * accHH[mt][i]);
                float hn = z * hv[mt][i] + (1.f - z) * c;
                bool msk = t < plen_[mt][i];
                float nh = msk ? hn : hv[mt][i];
                hv[mt][i] = nh;
                h_lds[(mg * 32 + mt * 16 + kg * 4 + i) * HSTR + d] = f2bf(nh);
                int pc = pblk + mg * 32 + mt * 16 + kg * 4 + i;
                int lkc = (pc < n_paths) ? gl[(size_t)pc * N_ML + t] : -1;
                if (msk && lkc >= 0) atomicAdd(&m[(size_t)lkc * 64 + d], hn);
            }
        }
        __syncthreads();  // h(t+1) visible
    }
    // writeback path_state
#pragma unroll
    for (int mt = 0; mt < 2; ++mt) {
#pragma unroll
        for (int i = 0; i < 4; ++i) {
            int pc = pblk + mg * 32 + mt * 16 + kg * 4 + i;
            if (pc < n_paths) ps[(size_t)pc * 64 + d] = hv[mt][i];
        }
    }
}

// ---- edge MLP (pre-folded): ls_new = con @ We + be ----
extern "C" __global__ void __launch_bounds__(256, 2)
edge_kernel(const float* __restrict__ ns, const float* __restrict__ lso,
            const float* __restrict__ m, const float* __restrict__ We,
            const float* __restrict__ be, const int* __restrict__ l2n,
            float* __restrict__ lsn, int n_links) {
    __shared__ float We_l[4096];
    __shared__ float be_l[32];
    __shared__ float con_l[8][128];
    int tid = threadIdx.x;
    for (int i = tid; i < 4096; i += 256) We_l[i] = We[i];
    if (tid < 32) be_l[tid] = be[tid];
    int li = tid >> 5, o = tid & 31;
    int l = blockIdx.x * 8 + li;
    if (l < n_links) {
        con_l[li][o] = ns[(size_t)l2n[l] * 32 + o];
        con_l[li][32 + o] = lso[(size_t)l * 32 + o];
        con_l[li][64 + o] = m[(size_t)l * 64 + o];
        con_l[li][96 + o] = m[(size_t)l * 64 + 32 + o];
    }
    __syncthreads();
    if (l >= n_links) return;
    float acc = be_l[o];
#pragma unroll 8
    for (int k = 0; k < 128; ++k) acc = fmaf(con_l[li][k], We_l[k * 32 + o], acc);
    lsn[(size_t)l * 32 + o] = acc;
}

// ---- ECCConv message: fused kernel-gen + matvec, agg via atomics ----
extern "C" __global__ void __launch_bounds__(256, 1)
ecc_kernel(const float* __restrict__ lsn, const float* __restrict__ ns,
           const float* __restrict__ wk, const float* __restrict__ bk,
           const int* __restrict__ senders, const int* __restrict__ receivers,
           float* __restrict__ agg, int n_links) {
    extern __shared__ float wk_l[];  // 32*1024 floats = 128 KB
    __shared__ float ls_s[8][32];
    __shared__ float ns_s[8][32];
    int tid = threadIdx.x;
    {
        const float4* a = (const float4*)wk;
        float4* la = (float4*)wk_l;
        for (int i = tid; i < 8192; i += 256) la[i] = a[i];
    }
    int li = tid >> 5, o = tid & 31;
    int l = blockIdx.x * 8 + li;
    if (l < n_links) {
        ls_s[li][o] = lsn[(size_t)l * 32 + o];
        ns_s[li][o] = ns[(size_t)senders[l] * 32 + o];
    }
    __syncthreads();
    if (l >= n_links) return;
    float acc = 0.f;
    for (int i = 0; i < 32; ++i) {
        float kio = bk[i * 32 + o];
#pragma unroll 8
        for (int j = 0; j < 32; ++j) kio = fmaf(ls_s[li][j], wk_l[j * 1024 + i * 32 + o], kio);
        acc = fmaf(ns_s[li][i], kio, acc);
    }
    atomicAdd(&agg[(size_t)receivers[l] * 32 + o], acc);
}

// ---- node update: ns_new = agg + ns_old @ wroot + broot ----
extern "C" __global__ void __launch_bounds__(256, 2)
node_kernel(const float* __restrict__ agg, const float* __restrict__ nso,
            const float* __restrict__ wroot, const float* __restrict__ broot,
            float* __restrict__ nsn, int n_nodes) {
    __shared__ float wr_l[1024];
    __shared__ float ns_s[8][32];
    int tid = threadIdx.x;
    for (int i = tid; i < 1024; i += 256) wr_l[i] = wroot[i];
    int ni = tid >> 5, o = tid & 31;
    int n = blockIdx.x * 8 + ni;
    if (n < n_nodes) ns_s[ni][o] = nso[(size_t)n * 32 + o];
    __syncthreads();
    if (n >= n_nodes) return;
    float acc = agg[(size_t)n * 32 + o] + broot[o];
#pragma unroll 8
    for (int k = 0; k < 32; ++k) acc = fmaf(ns_s[ni][k], wr_l[k * 32 + o], acc);
    nsn[(size_t)n * 32 + o] = acc;
}

// ---- readout: selu MLP + final head, 32 lanes per path ----
extern "C" __global__ void __launch_bounds__(256, 2)
readout_kernel(const float* __restrict__ ps, const float* __restrict__ w1,
               const float* __restrict__ b1, const float* __restrict__ w2,
               const float* __restrict__ b2, const float* __restrict__ fw,
               const float* __restrict__ fb, float* __restrict__ out, int n_paths) {
    __shared__ float w1_l[2048];
    __shared__ float w2_l[1024];
    __shared__ float fw_l[96];
    __shared__ float b1_l[32], b2_l[32];
    __shared__ float h_s[8][64];
    __shared__ float r1_s[8][32];
    int tid = threadIdx.x;
    for (int i = tid; i < 2048; i += 256) w1_l[i] = w1[i];
    for (int i = tid; i < 1024; i += 256) w2_l[i] = w2[i];
    if (tid < 96) fw_l[tid] = fw[tid];
    if (tid < 32) { b1_l[tid] = b1[tid]; b2_l[tid] = b2[tid]; }
    int li = tid >> 5, j = tid & 31;
    int p = blockIdx.x * 8 + li;
    bool ok = (p < n_paths);
    if (ok) {
        h_s[li][j] = ps[(size_t)p * 64 + j];
        h_s[li][32 + j] = ps[(size_t)p * 64 + 32 + j];
    }
    __syncthreads();
    float a = b1_l[j];
#pragma unroll 8
    for (int k = 0; k < 64; ++k) a = fmaf(h_s[li][k], w1_l[k * 32 + j], a);
    r1_s[li][j] = fselu(a);
    __syncthreads();
    float b = b2_l[j];
#pragma unroll 8
    for (int k = 0; k < 32; ++k) b = fmaf(r1_s[li][k], w2_l[k * 32 + j], b);
    float part = fselu(b) * fw_l[j] + h_s[li][j] * fw_l[32 + j] + h_s[li][32 + j] * fw_l[64 + j];
#pragma unroll
    for (int off = 16; off > 0; off >>= 1) part += __shfl_down(part, off, 32);
    if (j == 0 && ok) out[p] = part + fb[0];
}

extern "C" void kernel_launch(void* const* d_in, const int* in_sizes, int n_in,
                              void* d_out, int out_size, void* d_ws, size_t ws_size,
                              hipStream_t stream) {
    const float* link_init = (const float*)d_in[0];
    const float* node_init = (const float*)d_in[1];
    const float* path_init = (const float*)d_in[2];
    const float* gru_wx = (const float*)d_in[3];
    const float* gru_wh = (const float*)d_in[4];
    const float* gru_b = (const float*)d_in[5];
    const float* e_w1 = (const float*)d_in[6];
    const float* e_b1 = (const float*)d_in[7];
    const float* e_w2 = (const float*)d_in[8];
    const float* e_b2 = (const float*)d_in[9];
    const float* ecc_wk = (const float*)d_in[10];
    const float* ecc_bk = (const float*)d_in[11];
    const float* ecc_wroot = (const float*)d_in[12];
    const float* ecc_broot = (const float*)d_in[13];
    const float* r_w1 = (const float*)d_in[14];
    const float* r_b1 = (const float*)d_in[15];
    const float* r_w2 = (const float*)d_in[16];
    const float* r_b2 = (const float*)d_in[17];
    const float* f_w = (const float*)d_in[18];
    const float* f_b = (const float*)d_in[19];
    const int* p2l = (const int*)d_in[20];
    const int* sseq = (const int*)d_in[21];
    const int* l2p = (const int*)d_in[22];
    const int* n2p = (const int*)d_in[23];
    const int* l2n = (const int*)d_in[24];
    const int* senders = (const int*)d_in[25];
    const int* receivers = (const int*)d_in[26];

    const int nl = in_sizes[0];
    const int nn = in_sizes[1];
    const int np = in_sizes[2] / 2;
    const int E = in_sizes[20];

    char* base = (char*)d_ws;
    size_t off = 0;
    auto give = [&](size_t nbytes) -> void* {
        void* p = base + off;
        off += (nbytes + 255) & ~(size_t)255;
        return p;
    };
    float* ls0 = (float*)give((size_t)nl * 32 * 4);
    float* ls1 = (float*)give((size_t)nl * 32 * 4);
    float* ns0 = (float*)give((size_t)nn * 32 * 4);
    float* ns1 = (float*)give((size_t)nn * 32 * 4);
    float* ps = (float*)give((size_t)np * 64 * 4);
    float* m = (float*)give((size_t)nl * 64 * 4);
    float* agg = (float*)give((size_t)nn * 32 * 4);
    float* We = (float*)give(4096 * 4);
    float* be = (float*)give(32 * 4);
    int* gl = (int*)give((size_t)np * N_ML * 4);
    int* gn = (int*)give((size_t)np * N_ML * 4);
    int* lensb = (int*)give((size_t)np * 4);
    float* lsb[2] = {ls0, ls1};
    float* nsb[2] = {ns0, ns1};

    (void)hipFuncSetAttribute((const void*)ecc_kernel, hipFuncAttributeMaxDynamicSharedMemorySize,
                              ECC_SMEM);

    hipMemsetAsync(ls0, 0, (size_t)nl * 32 * 4, stream);
    hipMemsetAsync(ns0, 0, (size_t)nn * 32 * 4, stream);
    hipMemsetAsync(ps, 0, (size_t)np * 64 * 4, stream);
    hipMemsetAsync(gl, 0xFF, (size_t)np * N_ML * 4, stream);
    hipMemsetAsync(gn, 0xFF, (size_t)np * N_ML * 4, stream);
    hipMemsetAsync(lensb, 0, (size_t)np * 4, stream);

    prep_we_kernel<<<16, 256, 0, stream>>>(e_w1, e_b1, e_w2, e_b2, We, be);
    init_states_kernel<<<(np + 255) / 256, 256, 0, stream>>>(link_init, node_init, path_init,
                                                             ls0, ns0, ps, nl, nn, np);
    build_idx_kernel<<<(E + 255) / 256, 256, 0, stream>>>(p2l, sseq, l2p, n2p, gl, gn, lensb, E);

    int cur = 0;
    for (int it = 0; it < 2; ++it) {
        hipMemsetAsync(m, 0, (size_t)nl * 64 * 4, stream);
        gru_kernel<<<(np + 63) / 64, 512, 0, stream>>>(lsb[cur], nsb[cur], ps, m, gl, gn, lensb,
                                                       gru_wx, gru_wh, gru_b, np);
        edge_kernel<<<(nl + 7) / 8, 256, 0, stream>>>(nsb[cur], lsb[cur], m, We, be, l2n,
                                                      lsb[1 - cur], nl);
        hipMemsetAsync(agg, 0, (size_t)nn * 32 * 4, stream);
        ecc_kernel<<<(nl + 7) / 8, 256, ECC_SMEM, stream>>>(lsb[1 - cur], nsb[cur], ecc_wk, ecc_bk,
                                                            senders, receivers, agg, nl);
        node_kernel<<<(nn + 7) / 8, 256, 0, stream>>>(agg, nsb[cur], ecc_wroot, ecc_broot,
                                                      nsb[1 - cur], nn);
        cur ^= 1;
    }
    readout_kernel<<<(np + 7) / 8, 256, 0, stream>>>(ps, r_w1, r_b1, r_w2, r_b2, f_w, f_b,
                                                     (float*)d_out, np);
}